// Round 5
// baseline (416.173 us; speedup 1.0000x reference)
//
#include <hip/hip_runtime.h>
#include <math.h>

// x (2,16,2048,2048) fp32 -> d_out flat fp32 concat:
//   out  = softmax(x, -1)                [134217728]
//   q    = 64x64 blockwise int8 (as f32) [134217728]
//   s    = per-block scale               [32768]
//   z    = per-block zero                [32768]
//
// Single fused kernel: one 1024-thread block per 64-row strip (512 KB of x).
// Phase A reads the strip once (HBM), computes per-row max & 1/sum.
// Phase B re-reads the strip (L3-resident: 256 CU x 1 block x 512 KB = 128 MB
// in flight <= 256 MB Infinity Cache), computes softmax + per-64x64-tile
// int8 quant entirely in registers. NT stores keep writes from evicting
// the pending re-read data.

static constexpr int  COLS      = 2048;
static constexpr long long OUT_ELEMS = 134217728LL;
static constexpr int  NBLK      = 32768;   // 32 * 32 * 32 quant tiles

using v4f = __attribute__((ext_vector_type(4))) float;

__global__ __launch_bounds__(1024) void fused_kernel(
    const float* __restrict__ x,
    float* __restrict__ out, float* __restrict__ qout,
    float* __restrict__ sout, float* __restrict__ zout)
{
    const int b = blockIdx.x;        // 0..1023
    const int n = b >> 5;            // batch*head 0..31
    const int i = b & 31;            // row-block 0..31
    const int t = threadIdx.x;
    const int w = t >> 6;            // wave 0..15
    const int l = t & 63;

    const long long xbase = (long long)n * (COLS * (long long)COLS)
                          + (long long)(i * 64) * COLS;

    __shared__ float2 sst[64];       // per strip row: {max, 1/sum}

    // ---------------- Phase A: row stats (wave per row, 4 rounds) ----------
#pragma unroll
    for (int rr = 0; rr < 4; ++rr) {
        const int r = w + rr * 16;
        const float* rp = x + xbase + (long long)r * COLS;
        float4 v[8];
#pragma unroll
        for (int c = 0; c < 8; ++c)
            v[c] = *reinterpret_cast<const float4*>(rp + c * 256 + l * 4);

        float m = -INFINITY;
#pragma unroll
        for (int c = 0; c < 8; ++c)
            m = fmaxf(m, fmaxf(fmaxf(v[c].x, v[c].y), fmaxf(v[c].z, v[c].w)));
#pragma unroll
        for (int off = 32; off >= 1; off >>= 1)
            m = fmaxf(m, __shfl_xor(m, off, 64));

        float s = 0.0f;
#pragma unroll
        for (int c = 0; c < 8; ++c)
            s += __expf(v[c].x - m) + __expf(v[c].y - m) +
                 __expf(v[c].z - m) + __expf(v[c].w - m);
#pragma unroll
        for (int off = 32; off >= 1; off >>= 1)
            s += __shfl_xor(s, off, 64);

        if (l == 0) sst[r] = make_float2(m, 1.0f / s);
    }
    __syncthreads();

    // ---------------- Phase B: wave w handles quant tiles j = w, w+16 ------
#pragma unroll
    for (int jj = 0; jj < 2; ++jj) {
        const int j = w + jj * 16;               // column tile 0..31
        const long long tbase = xbase + j * 64;  // tile top-left in x/out
        const int cl = (l & 15) * 4;             // lane's cols within tile
        const int rl = l >> 4;                   // lane's base row 0..3

        float4 p[16];
        float mn = INFINITY, mx = -INFINITY;
#pragma unroll
        for (int k = 0; k < 16; ++k) {
            const int r = rl + 4 * k;
            const float2 st = sst[r];
            const float4 v = *reinterpret_cast<const float4*>(
                x + tbase + (long long)r * COLS + cl);
            float4 pv;
            pv.x = __expf(v.x - st.x) * st.y;
            pv.y = __expf(v.y - st.x) * st.y;
            pv.z = __expf(v.z - st.x) * st.y;
            pv.w = __expf(v.w - st.x) * st.y;
            p[k] = pv;
            mn = fminf(mn, fminf(fminf(pv.x, pv.y), fminf(pv.z, pv.w)));
            mx = fmaxf(mx, fmaxf(fmaxf(pv.x, pv.y), fmaxf(pv.z, pv.w)));
        }
        // full-wave butterfly: every lane gets tile min/max
#pragma unroll
        for (int off = 32; off >= 1; off >>= 1) {
            mn = fminf(mn, __shfl_xor(mn, off, 64));
            mx = fmaxf(mx, __shfl_xor(mx, off, 64));
        }

        const float sc  = (mx - mn) / 255.0f;
        const float d   = sc + 1e-10f;
        const float zz  = -mn / d - 128.0f;
        const float rcp = 1.0f / d;
        const int b4 = (n << 10) + (i << 5) + j;
        if (l == 0) { sout[b4] = sc; zout[b4] = zz; }

        float* __restrict__ qb = qout + (long long)b4 * 4096 + cl;
#pragma unroll
        for (int k = 0; k < 16; ++k) {
            const int r = rl + 4 * k;
            const float4 pv = p[k];
            __builtin_nontemporal_store(*(const v4f*)&pv,
                (v4f*)(out + tbase + (long long)r * COLS + cl));
            float4 qv;
            qv.x = roundf(fminf(fmaxf(pv.x * rcp + zz, -128.0f), 127.0f));
            qv.y = roundf(fminf(fmaxf(pv.y * rcp + zz, -128.0f), 127.0f));
            qv.z = roundf(fminf(fmaxf(pv.z * rcp + zz, -128.0f), 127.0f));
            qv.w = roundf(fminf(fmaxf(pv.w * rcp + zz, -128.0f), 127.0f));
            __builtin_nontemporal_store(*(const v4f*)&qv, (v4f*)(qb + r * 64));
        }
    }
}

extern "C" void kernel_launch(void* const* d_in, const int* in_sizes, int n_in,
                              void* d_out, int out_size, void* d_ws, size_t ws_size,
                              hipStream_t stream) {
    const float* x = (const float*)d_in[0];
    float* out  = (float*)d_out;
    float* qout = out + OUT_ELEMS;
    float* sout = qout + OUT_ELEMS;
    float* zout = sout + NBLK;

    fused_kernel<<<1024, 1024, 0, stream>>>(x, out, qout, sout, zout);
}

// Round 6
// 372.138 us; speedup vs baseline: 1.1183x; 1.1183x over previous
//
#include <hip/hip_runtime.h>
#include <math.h>

// x (2,16,2048,2048) fp32 -> d_out flat fp32 concat:
//   out  = softmax(x, -1)                [134217728]
//   q    = 64x64 blockwise int8 (as f32) [134217728]
//   s    = per-block scale               [32768]
//   z    = per-block zero                [32768]
//
// Chunked 2-pass: 8 chunks of 8192 rows (64 MB of x). For each chunk,
// rowstats(c) then panels(c) launched back-to-back; stream order means the
// panel kernel re-reads x data the rowstats kernel pulled into Infinity
// Cache microseconds earlier (64 MB << 256 MB L3) -> guaranteed hits.
// Panel x loads are CACHED (harvest L3); all bulk stores NT (don't thrash).

static constexpr int  COLS      = 2048;
static constexpr long long OUT_ELEMS = 134217728LL;
static constexpr int  NBLK      = 32768;    // 32*32*32 quant tiles
static constexpr int  NCHUNK    = 8;
static constexpr int  ROWS_PER_CHUNK   = 8192;   // 65536 / 8
static constexpr int  PANELS_PER_CHUNK = 1024;   // 8192 panels / 8

using v4f = __attribute__((ext_vector_type(4))) float;

// ---------------- Kernel 1: per-row max and 1/sum(exp(x-max)) ----------------
// One wave per row, 4 rows per 256-thread block. Cached loads populate L3.
__global__ __launch_bounds__(256) void rowstats_kernel(
    const float* __restrict__ x, float* __restrict__ stats, int chunk)
{
    const int lane = threadIdx.x & 63;
    const int wave = threadIdx.x >> 6;
    const long long row = (long long)chunk * ROWS_PER_CHUNK
                        + (long long)blockIdx.x * 4 + wave;
    const float* rp = x + row * COLS;

    float4 v[8];
#pragma unroll
    for (int c = 0; c < 8; ++c)
        v[c] = *reinterpret_cast<const float4*>(rp + c * 256 + lane * 4);

    float m = -INFINITY;
#pragma unroll
    for (int c = 0; c < 8; ++c)
        m = fmaxf(m, fmaxf(fmaxf(v[c].x, v[c].y), fmaxf(v[c].z, v[c].w)));
#pragma unroll
    for (int off = 32; off >= 1; off >>= 1)
        m = fmaxf(m, __shfl_xor(m, off, 64));

    float s = 0.0f;
#pragma unroll
    for (int c = 0; c < 8; ++c)
        s += __expf(v[c].x - m) + __expf(v[c].y - m) +
             __expf(v[c].z - m) + __expf(v[c].w - m);
#pragma unroll
    for (int off = 32; off >= 1; off >>= 1)
        s += __shfl_xor(s, off, 64);

    if (lane == 0) {
        stats[row * 2 + 0] = m;
        stats[row * 2 + 1] = 1.0f / s;
    }
}

// ---------------- Kernel 2: 64x256 panel = 4 column-tiles per block ----------
// 1024 blocks per chunk. Wave w handles rows {4k+w}; lane l covers cols
// [l*4, l*4+4) -> 1 KB contiguous per wave for x reads and out writes.
__global__ __launch_bounds__(256) void panel_kernel(
    const float* __restrict__ x, const float* __restrict__ stats,
    float* __restrict__ out, float* __restrict__ qout,
    float* __restrict__ sout, float* __restrict__ zout, int chunk)
{
    const int b  = chunk * PANELS_PER_CHUNK + blockIdx.x;  // global panel id
    const int n  = b >> 8;             // 0..31
    const int i  = (b >> 3) & 31;      // row-block
    const int jg = b & 7;              // group of 4 column-tiles
    const int t  = threadIdx.x;
    const int w  = t >> 6;             // wave 0..3
    const int l  = t & 63;

    const long long xbase = (long long)n * (COLS * (long long)COLS)
                          + (long long)(i * 64) * COLS + jg * 256;
    const int growbase = (n << 11) + i * 64;

    float4 p[16];
    float mn = INFINITY, mx = -INFINITY;
#pragma unroll
    for (int k = 0; k < 16; ++k) {
        const int r = (k << 2) + w;
        const float2 st = *reinterpret_cast<const float2*>(
            stats + (long long)(growbase + r) * 2);
        const float4 v = *reinterpret_cast<const float4*>(
            x + xbase + (long long)r * COLS + l * 4);      // cached: L3 hit
        float4 pv;
        pv.x = __expf(v.x - st.x) * st.y;
        pv.y = __expf(v.y - st.x) * st.y;
        pv.z = __expf(v.z - st.x) * st.y;
        pv.w = __expf(v.w - st.x) * st.y;
        p[k] = pv;
        mn = fminf(mn, fminf(fminf(pv.x, pv.y), fminf(pv.z, pv.w)));
        mx = fmaxf(mx, fmaxf(fmaxf(pv.x, pv.y), fmaxf(pv.z, pv.w)));
    }
    // reduce within each 16-lane group (one group per tile)
#pragma unroll
    for (int off = 8; off >= 1; off >>= 1) {
        mn = fminf(mn, __shfl_xor(mn, off, 64));
        mx = fmaxf(mx, __shfl_xor(mx, off, 64));
    }

    __shared__ float  smn[4][4], smx[4][4];   // [wave][tile]
    __shared__ float2 sbc[4];                 // per tile: {z, 1/(s+eps)}
    if ((l & 15) == 0) { smn[w][l >> 4] = mn; smx[w][l >> 4] = mx; }
    __syncthreads();
    if (t < 4) {
        const float bmn = fminf(fminf(smn[0][t], smn[1][t]),
                                fminf(smn[2][t], smn[3][t]));
        const float bmx = fmaxf(fmaxf(smx[0][t], smx[1][t]),
                                fmaxf(smx[2][t], smx[3][t]));
        const float sc = (bmx - bmn) / 255.0f;
        const float d  = sc + 1e-10f;
        const float zz = -bmn / d - 128.0f;
        const int b4 = (n << 10) + (i << 5) + (jg << 2) + t;
        sout[b4] = sc;
        zout[b4] = zz;
        sbc[t] = make_float2(zz, 1.0f / d);
    }
    __syncthreads();

    const int   tl  = l >> 4;
    const float2 bc = sbc[tl];
    float* __restrict__ qb = qout
        + (long long)((n << 10) + (i << 5) + (jg << 2)) * 4096
        + tl * 4096 + (l & 15) * 4;

#pragma unroll
    for (int k = 0; k < 16; ++k) {
        const int r = (k << 2) + w;
        const float4 pv = p[k];
        __builtin_nontemporal_store(*(const v4f*)&pv,
            (v4f*)(out + xbase + (long long)r * COLS + l * 4));
        float4 qv;
        qv.x = roundf(fminf(fmaxf(pv.x * bc.y + bc.x, -128.0f), 127.0f));
        qv.y = roundf(fminf(fmaxf(pv.y * bc.y + bc.x, -128.0f), 127.0f));
        qv.z = roundf(fminf(fmaxf(pv.z * bc.y + bc.x, -128.0f), 127.0f));
        qv.w = roundf(fminf(fmaxf(pv.w * bc.y + bc.x, -128.0f), 127.0f));
        __builtin_nontemporal_store(*(const v4f*)&qv, (v4f*)(qb + r * 64));
    }
}

extern "C" void kernel_launch(void* const* d_in, const int* in_sizes, int n_in,
                              void* d_out, int out_size, void* d_ws, size_t ws_size,
                              hipStream_t stream) {
    const float* x = (const float*)d_in[0];
    float* out  = (float*)d_out;
    float* qout = out + OUT_ELEMS;
    float* sout = qout + OUT_ELEMS;
    float* zout = sout + NBLK;
    float* stats = (float*)d_ws;   // 65536 * 2 floats = 512 KB

    for (int c = 0; c < NCHUNK; ++c) {
        rowstats_kernel<<<ROWS_PER_CHUNK / 4, 256, 0, stream>>>(x, stats, c);
        panel_kernel<<<PANELS_PER_CHUNK, 256, 0, stream>>>(
            x, stats, out, qout, sout, zout, c);
    }
}